// Round 7
// baseline (1705.153 us; speedup 1.0000x reference)
//
#include <hip/hip_runtime.h>

// SP_DNN: two fused 1->256->256->256->256 MLPs (sin activations) + strided rowwise dot.
// fp16 MFMA 32x32x16, fp32 accumulate. 512-thread blocks (8 waves), each wave owns a
// 32-channel output band -> tiny per-wave register state (acc 32 + hold 16), enabling
// 4 waves/SIMD (16 waves/CU, 2 blocks) for pipe overlap via TLP. Activations in one
// 32 KB LDS buffer; weights from L2-resident packed buffer straight into A-fragments.

typedef _Float16 f16x8 __attribute__((ext_vector_type(8)));
typedef _Float16 f16x4 __attribute__((ext_vector_type(4)));
typedef float f32x4 __attribute__((ext_vector_type(4)));
typedef float f32x16 __attribute__((ext_vector_type(16)));

// Swizzled hbuf byte offset: row m (0..63, 512 B stride), kbyte in [0,512).
// 16B-unit index XORed with (m&7): B-reads cover all 32 banks per 8-lane group.
__device__ __forceinline__ int hswz(int m, int kbyte) {
    return m * 512 + ((((kbyte >> 4) ^ (m & 7)) & 31) << 4) + (kbyte & 15);
}

// ---------------------------------------------------------------------------
// Prepack: 6 matrices W[k][n] (256x256 f32, k-major) -> fp16 A-fragment-major
// for mfma_32x32x16, 32-channel wave bands:
//   r = ks*4096 + wv*512 + l*8 + j   (ks=kstep 0..15, wv=wave 0..7, l=lane, j=0..7)
//   n = wv*32 + (l&31), k = ks*16 + ((l>>5)&1)*8 + j
// Per (ks,wv): contiguous 1 KB, lane-coalesced.
// ---------------------------------------------------------------------------
__global__ void prepack(const float* __restrict__ xW1, const float* __restrict__ xW2,
                        const float* __restrict__ xW3, const float* __restrict__ tW1,
                        const float* __restrict__ tW2, const float* __restrict__ tW3,
                        _Float16* __restrict__ dst)
{
    int g = blockIdx.x * 256 + threadIdx.x;   // 6*65536 threads exactly
    int L = g >> 16;
    int r = g & 65535;
    int j  = r & 7;
    int l  = (r >> 3) & 63;
    int wv = (r >> 9) & 7;
    int ks = (r >> 12) & 15;
    const float* W;
    switch (L) {
        case 0: W = xW1; break;
        case 1: W = xW2; break;
        case 2: W = xW3; break;
        case 3: W = tW1; break;
        case 4: W = tW2; break;
        default: W = tW3; break;
    }
    int n = wv * 32 + (l & 31);
    int k = ks * 16 + ((l >> 5) & 1) * 8 + j;
    dst[g] = (_Float16)W[k * 256 + n];
}

// ---------------------------------------------------------------------------
// Main fused kernel. Block = 512 threads (8 waves), tile = 64 rows.
// ---------------------------------------------------------------------------

__device__ __forceinline__ void layer0_scalar(
    const float* __restrict__ x, int row0, int sel,
    const float* __restrict__ W0, const float* __restrict__ b0,
    _Float16* __restrict__ hb, int tid)
{
    int m = tid >> 3;        // 64 rows, 8 threads per row
    int q = tid & 7;         // each thread does 32 of the 256 channels
    float xv = x[(row0 + m) * 2 + sel];
#pragma unroll
    for (int g = 0; g < 4; ++g) {
        int n0 = q * 32 + g * 8;
        f16x8 hv;
#pragma unroll
        for (int e = 0; e < 8; ++e) {
            float z = fmaf(xv, W0[n0 + e], b0[n0 + e]);
            hv[e] = (_Float16)__sinf(z);
        }
        *(f16x8*)((char*)hb + hswz(m, n0 * 2)) = hv;
    }
}

// One 256->256 layer. Wave computes its 32-channel band for all 64 rows
// (2 row-tiles of 32). A from global (L2-resident, coalesced 1 KB/load),
// B from LDS. D (32x32): ch_local = (reg&3) + 8*(reg>>2) + 4*(lane>>5),
// row m = rowtile*32 + (lane&31).
template<bool WRITE_H>
__device__ __forceinline__ void gemm_layer(
    const _Float16* __restrict__ Wl,     // packed layer base (65536 elems)
    const float* __restrict__ bias,      // 256 f32 (only used if WRITE_H)
    _Float16* __restrict__ hb,
    f32x16 acc[2],
    int lane, int wave)
{
    acc[0] = (f32x16){};
    acc[1] = (f32x16){};

    const _Float16* ab = Wl + wave * 512 + lane * 8;
    const int m0 = lane & 31;
    const int kq = (lane >> 5) * 16;     // k-half byte offset within 32-byte step

#pragma unroll
    for (int ks = 0; ks < 16; ++ks) {
        f16x8 afr = *(const f16x8*)(ab + ks * 4096);
        f16x8 b0 = *(const f16x8*)((const char*)hb + hswz(m0,      ks * 32 + kq));
        f16x8 b1 = *(const f16x8*)((const char*)hb + hswz(32 + m0, ks * 32 + kq));
        acc[0] = __builtin_amdgcn_mfma_f32_32x32x16_f16(afr, b0, acc[0], 0, 0, 0);
        acc[1] = __builtin_amdgcn_mfma_f32_32x32x16_f16(afr, b1, acc[1], 0, 0, 0);
    }
    __syncthreads();           // all waves done READING hb for this layer
    if (WRITE_H) {
#pragma unroll
        for (int gg = 0; gg < 4; ++gg) {
            int ch = wave * 32 + 8 * gg + 4 * (lane >> 5);   // 4 consecutive channels
            f32x4 bv = *(const f32x4*)&bias[ch];
#pragma unroll
            for (int t = 0; t < 2; ++t) {
                f16x4 hv;
                hv[0] = (_Float16)__sinf(acc[t][gg * 4 + 0] + bv[0]);
                hv[1] = (_Float16)__sinf(acc[t][gg * 4 + 1] + bv[1]);
                hv[2] = (_Float16)__sinf(acc[t][gg * 4 + 2] + bv[2]);
                hv[3] = (_Float16)__sinf(acc[t][gg * 4 + 3] + bv[3]);
                *(f16x4*)((char*)hb + hswz(t * 32 + m0, ch * 2)) = hv;
            }
        }
        __syncthreads();       // writes visible before next layer's B reads
    }
}

__global__ __launch_bounds__(512, 4)
void mlp_fused(const float* __restrict__ x,
               const float* __restrict__ xW0, const float* __restrict__ xb0,
               const float* __restrict__ xb1, const float* __restrict__ xb2,
               const float* __restrict__ xb3,
               const float* __restrict__ tW0, const float* __restrict__ tb0,
               const float* __restrict__ tb1, const float* __restrict__ tb2,
               const float* __restrict__ tb3,
               const _Float16* __restrict__ Wp,
               float* __restrict__ out)
{
    __shared__ __align__(16) _Float16 hbuf[64 * 256];   // 32 KB

    const int tid = threadIdx.x;
    const int lane = tid & 63;
    const int wave = tid >> 6;          // 0..7
    const int m0 = lane & 31;
    const int q2 = lane >> 5;
    const int row0 = blockIdx.x * 64;

    f32x16 acc[2];         // per-layer accumulator (32 regs)

    // ----- x-MLP -----
    layer0_scalar(x, row0, 0, xW0, xb0, hbuf, tid);
    __syncthreads();
    gemm_layer<true >(Wp + 0 * 65536, xb1, hbuf, acc, lane, wave);
    gemm_layer<true >(Wp + 1 * 65536, xb2, hbuf, acc, lane, wave);
    gemm_layer<false>(Wp + 2 * 65536, nullptr, hbuf, acc, lane, wave);
    // (ends with read-done barrier -> hbuf free)

    // Hold x-MLP output as packed f16 with bias folded (16 regs).
    f16x4 xh[2][4];
#pragma unroll
    for (int gg = 0; gg < 4; ++gg) {
        int ch = wave * 32 + 8 * gg + 4 * q2;
        f32x4 bv = *(const f32x4*)&xb3[ch];
#pragma unroll
        for (int t = 0; t < 2; ++t) {
            xh[t][gg][0] = (_Float16)(acc[t][gg * 4 + 0] + bv[0]);
            xh[t][gg][1] = (_Float16)(acc[t][gg * 4 + 1] + bv[1]);
            xh[t][gg][2] = (_Float16)(acc[t][gg * 4 + 2] + bv[2]);
            xh[t][gg][3] = (_Float16)(acc[t][gg * 4 + 3] + bv[3]);
        }
    }

    // ----- t-MLP -----
    layer0_scalar(x, row0, 1, tW0, tb0, hbuf, tid);
    __syncthreads();
    gemm_layer<true >(Wp + 3 * 65536, tb1, hbuf, acc, lane, wave);
    gemm_layer<true >(Wp + 4 * 65536, tb2, hbuf, acc, lane, wave);
    gemm_layer<false>(Wp + 5 * 65536, nullptr, hbuf, acc, lane, wave);
    // (ends with barrier -> hbuf reusable as reduce scratch)

    // ----- combine: even/odd strided dot, fp32 -----
    // channel parity = (element index & 1); ch_local = 8*gg + 4*q2 + e
    float ev[2] = {0.f, 0.f};
    float od[2] = {0.f, 0.f};
#pragma unroll
    for (int gg = 0; gg < 4; ++gg) {
        int ch = wave * 32 + 8 * gg + 4 * q2;
        f32x4 tb = *(const f32x4*)&tb3[ch];
#pragma unroll
        for (int t = 0; t < 2; ++t) {
            float a0 = (float)xh[t][gg][0], c0 = acc[t][gg * 4 + 0] + tb[0];
            float a1 = (float)xh[t][gg][1], c1 = acc[t][gg * 4 + 1] + tb[1];
            float a2 = (float)xh[t][gg][2], c2 = acc[t][gg * 4 + 2] + tb[2];
            float a3 = (float)xh[t][gg][3], c3 = acc[t][gg * 4 + 3] + tb[3];
            ev[t] += a0 * c0 + a2 * c2;
            od[t] += a1 * c1 + a3 * c3;
        }
    }
#pragma unroll
    for (int t = 0; t < 2; ++t) {        // fold the two k-halves (q2 pair)
        ev[t] += __shfl_xor(ev[t], 32, 64);
        od[t] += __shfl_xor(od[t], 32, 64);
    }

    float* red = (float*)hbuf;           // 8 waves x 128 floats = 4 KB
    if (lane < 32) {
#pragma unroll
        for (int t = 0; t < 2; ++t) {
            red[wave * 128 + t * 64 + m0 * 2 + 0] = ev[t];
            red[wave * 128 + t * 64 + m0 * 2 + 1] = od[t];
        }
    }
    __syncthreads();
    if (tid < 128) {                     // sum 8 wave partials; coalesced 512 B store
        float s = 0.f;
#pragma unroll
        for (int w = 0; w < 8; ++w)
            s += red[w * 128 + tid];
        out[row0 * 2 + tid] = s;
    }
}

// ---------------------------------------------------------------------------
extern "C" void kernel_launch(void* const* d_in, const int* in_sizes, int n_in,
                              void* d_out, int out_size, void* d_ws, size_t ws_size,
                              hipStream_t stream)
{
    const float* x   = (const float*)d_in[0];
    const float* xW0 = (const float*)d_in[1];
    const float* xb0 = (const float*)d_in[2];
    const float* xW1 = (const float*)d_in[3];
    const float* xb1 = (const float*)d_in[4];
    const float* xW2 = (const float*)d_in[5];
    const float* xb2 = (const float*)d_in[6];
    const float* xW3 = (const float*)d_in[7];
    const float* xb3 = (const float*)d_in[8];
    const float* tW0 = (const float*)d_in[9];
    const float* tb0 = (const float*)d_in[10];
    const float* tW1 = (const float*)d_in[11];
    const float* tb1 = (const float*)d_in[12];
    const float* tW2 = (const float*)d_in[13];
    const float* tb2 = (const float*)d_in[14];
    const float* tW3 = (const float*)d_in[15];
    const float* tb3 = (const float*)d_in[16];

    _Float16* Wp = (_Float16*)d_ws;          // 6*65536 fp16 = 768 KB
    const int N = in_sizes[0] / 2;           // 1,000,000 (divisible by 64)

    prepack<<<1536, 256, 0, stream>>>(xW1, xW2, xW3, tW1, tW2, tW3, Wp);
    mlp_fused<<<N / 64, 512, 0, stream>>>(x, xW0, xb0, xb1, xb2, xb3,
                                          tW0, tb0, tb1, tb2, tb3,
                                          Wp, (float*)d_out);
}

// Round 8
// 1231.965 us; speedup vs baseline: 1.3841x; 1.3841x over previous
//
#include <hip/hip_runtime.h>

// SP_DNN: two fused 1->256->256->256->256 MLPs (sin activations) + strided rowwise dot.
// fp16 MFMA 16x16x32 (f32x4 acc tiles - proven codegen), 512-thread blocks (8 waves),
// each wave owns a 32-channel band: acc 32 + hold 16 regs -> ~100 unified regs, fits
// __launch_bounds__(512,4) = 4 waves/SIMD (16 waves/CU, 2 barrier groups) for pipe
// overlap. Activations in one 32 KB LDS buffer; weights from L2-resident packed
// buffer straight into A-fragment registers.

typedef _Float16 f16x8 __attribute__((ext_vector_type(8)));
typedef _Float16 f16x4 __attribute__((ext_vector_type(4)));
typedef float f32x4 __attribute__((ext_vector_type(4)));

// Swizzled hbuf byte offset: row m (0..63, 512 B stride), kbyte in [0,512).
// 16B-unit index XORed with (m&7): B-reads cover all 32 banks per 8-lane group.
__device__ __forceinline__ int hswz(int m, int kbyte) {
    return m * 512 + ((((kbyte >> 4) ^ (m & 7)) & 31) << 4) + (kbyte & 15);
}

// ---------------------------------------------------------------------------
// Prepack: 6 matrices W[k][n] (256x256 f32, k-major) -> fp16 A-fragment-major
// for mfma_16x16x32 with 32-channel wave bands:
//   idx = ks*8192 + wv*1024 + nt*512 + lane*8 + j
//   n = wv*32 + nt*16 + (lane&15), k = ks*32 + (lane>>4)*8 + j
// Per (ks,wv,nt): contiguous 512-elem (1 KB) lane-coalesced chunk.
// ---------------------------------------------------------------------------
__global__ void prepack(const float* __restrict__ xW1, const float* __restrict__ xW2,
                        const float* __restrict__ xW3, const float* __restrict__ tW1,
                        const float* __restrict__ tW2, const float* __restrict__ tW3,
                        _Float16* __restrict__ dst)
{
    int g = blockIdx.x * 256 + threadIdx.x;   // 6*65536 threads exactly
    int L = g >> 16;
    int r = g & 65535;
    int j    = r & 7;
    int lane = (r >> 3) & 63;
    int nt   = (r >> 9) & 1;
    int wv   = (r >> 10) & 7;
    int ks   = (r >> 13) & 7;
    const float* W;
    switch (L) {
        case 0: W = xW1; break;
        case 1: W = xW2; break;
        case 2: W = xW3; break;
        case 3: W = tW1; break;
        case 4: W = tW2; break;
        default: W = tW3; break;
    }
    int n = wv * 32 + nt * 16 + (lane & 15);
    int k = ks * 32 + (lane >> 4) * 8 + j;
    dst[g] = (_Float16)W[k * 256 + n];
}

// ---------------------------------------------------------------------------
// Main fused kernel. Block = 512 threads (8 waves), tile = 64 rows.
// ---------------------------------------------------------------------------

__device__ __forceinline__ void layer0_scalar(
    const float* __restrict__ x, int row0, int sel,
    const float* __restrict__ W0, const float* __restrict__ b0,
    _Float16* __restrict__ hb, int tid)
{
    int m = tid >> 3;        // 64 rows, 8 threads per row
    int q = tid & 7;         // each thread does 32 of the 256 channels
    float xv = x[(row0 + m) * 2 + sel];
#pragma unroll
    for (int g = 0; g < 4; ++g) {
        int n0 = q * 32 + g * 8;
        f16x8 hv;
#pragma unroll
        for (int e = 0; e < 8; ++e) {
            float z = fmaf(xv, W0[n0 + e], b0[n0 + e]);
            hv[e] = (_Float16)__sinf(z);
        }
        *(f16x8*)((char*)hb + hswz(m, n0 * 2)) = hv;
    }
}

// One 256->256 layer. Wave computes its 32-channel band (2 n-tiles of 16) for
// all 64 rows (4 m-tiles). A from global (L2-resident, coalesced 1 KB loads);
// B from LDS. D layout per tile: col=lane&15 = row m, row=quad*4+r = channel.
template<bool WRITE_H>
__device__ __forceinline__ void gemm_layer(
    const _Float16* __restrict__ Wl,     // packed layer base (65536 elems)
    const float* __restrict__ bias,      // 256 f32 (only used if WRITE_H)
    _Float16* __restrict__ hb,
    f32x4 acc[2][4],
    int lane, int ln, int quad, int wave)
{
    f32x4 zero = {0.f, 0.f, 0.f, 0.f};
#pragma unroll
    for (int nt = 0; nt < 2; ++nt)
#pragma unroll
        for (int mt = 0; mt < 4; ++mt)
            acc[nt][mt] = zero;

    const _Float16* ab = Wl + wave * 1024 + lane * 8;

#pragma unroll
    for (int ks = 0; ks < 8; ++ks) {
        f16x8 afr[2], bfr[4];
#pragma unroll
        for (int nt = 0; nt < 2; ++nt)
            afr[nt] = *(const f16x8*)(ab + ks * 8192 + nt * 512);
#pragma unroll
        for (int mt = 0; mt < 4; ++mt)
            bfr[mt] = *(const f16x8*)((const char*)hb +
                                      hswz(mt * 16 + ln, ks * 64 + quad * 16));
#pragma unroll
        for (int nt = 0; nt < 2; ++nt)
#pragma unroll
            for (int mt = 0; mt < 4; ++mt)
                acc[nt][mt] = __builtin_amdgcn_mfma_f32_16x16x32_f16(
                    afr[nt], bfr[mt], acc[nt][mt], 0, 0, 0);
    }
    __syncthreads();           // all waves done READING hb for this layer
    if (WRITE_H) {
#pragma unroll
        for (int nt = 0; nt < 2; ++nt) {
            int ch = wave * 32 + nt * 16 + quad * 4;         // 4 consecutive channels
            f32x4 bv = *(const f32x4*)&bias[ch];
#pragma unroll
            for (int mt = 0; mt < 4; ++mt) {
                f16x4 hv;
                hv[0] = (_Float16)__sinf(acc[nt][mt][0] + bv[0]);
                hv[1] = (_Float16)__sinf(acc[nt][mt][1] + bv[1]);
                hv[2] = (_Float16)__sinf(acc[nt][mt][2] + bv[2]);
                hv[3] = (_Float16)__sinf(acc[nt][mt][3] + bv[3]);
                *(f16x4*)((char*)hb + hswz(mt * 16 + ln, ch * 2)) = hv;
            }
        }
        __syncthreads();       // writes visible before next layer's B reads
    }
}

__global__ __launch_bounds__(512, 4)
void mlp_fused(const float* __restrict__ x,
               const float* __restrict__ xW0, const float* __restrict__ xb0,
               const float* __restrict__ xb1, const float* __restrict__ xb2,
               const float* __restrict__ xb3,
               const float* __restrict__ tW0, const float* __restrict__ tb0,
               const float* __restrict__ tb1, const float* __restrict__ tb2,
               const float* __restrict__ tb3,
               const _Float16* __restrict__ Wp,
               float* __restrict__ out)
{
    __shared__ __align__(16) _Float16 hbuf[64 * 256];   // 32 KB

    const int tid = threadIdx.x;
    const int lane = tid & 63;
    const int wave = tid >> 6;          // 0..7
    const int ln = lane & 15;
    const int quad = lane >> 4;
    const int row0 = blockIdx.x * 64;

    f32x4 acc[2][4];       // per-layer accumulator (32 regs)

    // ----- x-MLP -----
    layer0_scalar(x, row0, 0, xW0, xb0, hbuf, tid);
    __syncthreads();
    gemm_layer<true >(Wp + 0 * 65536, xb1, hbuf, acc, lane, ln, quad, wave);
    gemm_layer<true >(Wp + 1 * 65536, xb2, hbuf, acc, lane, ln, quad, wave);
    gemm_layer<false>(Wp + 2 * 65536, nullptr, hbuf, acc, lane, ln, quad, wave);
    // (ends with read-done barrier -> hbuf free)

    // Hold x-MLP output as packed f16 with bias folded (16 regs).
    f16x4 xh[2][4];
#pragma unroll
    for (int nt = 0; nt < 2; ++nt) {
        int ch = wave * 32 + nt * 16 + quad * 4;
        f32x4 bv = *(const f32x4*)&xb3[ch];
#pragma unroll
        for (int mt = 0; mt < 4; ++mt) {
            xh[nt][mt][0] = (_Float16)(acc[nt][mt][0] + bv[0]);
            xh[nt][mt][1] = (_Float16)(acc[nt][mt][1] + bv[1]);
            xh[nt][mt][2] = (_Float16)(acc[nt][mt][2] + bv[2]);
            xh[nt][mt][3] = (_Float16)(acc[nt][mt][3] + bv[3]);
        }
    }

    // ----- t-MLP -----
    layer0_scalar(x, row0, 1, tW0, tb0, hbuf, tid);
    __syncthreads();
    gemm_layer<true >(Wp + 3 * 65536, tb1, hbuf, acc, lane, ln, quad, wave);
    gemm_layer<true >(Wp + 4 * 65536, tb2, hbuf, acc, lane, ln, quad, wave);
    gemm_layer<false>(Wp + 5 * 65536, nullptr, hbuf, acc, lane, ln, quad, wave);
    // (ends with barrier -> hbuf reusable as reduce scratch)

    // ----- combine: even/odd strided dot, fp32 -----
    // channel = wave*32 + nt*16 + quad*4 + e; parity = e&1.
    float ev[4] = {0.f, 0.f, 0.f, 0.f};
    float od[4] = {0.f, 0.f, 0.f, 0.f};
#pragma unroll
    for (int nt = 0; nt < 2; ++nt) {
        int ch = wave * 32 + nt * 16 + quad * 4;
        f32x4 tb = *(const f32x4*)&tb3[ch];
#pragma unroll
        for (int mt = 0; mt < 4; ++mt) {
            float a0 = (float)xh[nt][mt][0], c0 = acc[nt][mt][0] + tb[0];
            float a1 = (float)xh[nt][mt][1], c1 = acc[nt][mt][1] + tb[1];
            float a2 = (float)xh[nt][mt][2], c2 = acc[nt][mt][2] + tb[2];
            float a3 = (float)xh[nt][mt][3], c3 = acc[nt][mt][3] + tb[3];
            ev[mt] += a0 * c0 + a2 * c2;
            od[mt] += a1 * c1 + a3 * c3;
        }
    }
#pragma unroll
    for (int mt = 0; mt < 4; ++mt) {     // reduce over the 4 quads
        ev[mt] += __shfl_xor(ev[mt], 16, 64);
        ev[mt] += __shfl_xor(ev[mt], 32, 64);
        od[mt] += __shfl_xor(od[mt], 16, 64);
        od[mt] += __shfl_xor(od[mt], 32, 64);
    }

    float* red = (float*)hbuf;           // 8 waves x 128 floats = 4 KB
    if (lane < 16) {
#pragma unroll
        for (int mt = 0; mt < 4; ++mt) {
            red[wave * 128 + (mt * 16 + lane) * 2 + 0] = ev[mt];
            red[wave * 128 + (mt * 16 + lane) * 2 + 1] = od[mt];
        }
    }
    __syncthreads();
    if (tid < 128) {                     // sum 8 wave partials; coalesced 512 B store
        float s = 0.f;
#pragma unroll
        for (int w = 0; w < 8; ++w)
            s += red[w * 128 + tid];
        out[row0 * 2 + tid] = s;
    }
}

// ---------------------------------------------------------------------------
extern "C" void kernel_launch(void* const* d_in, const int* in_sizes, int n_in,
                              void* d_out, int out_size, void* d_ws, size_t ws_size,
                              hipStream_t stream)
{
    const float* x   = (const float*)d_in[0];
    const float* xW0 = (const float*)d_in[1];
    const float* xb0 = (const float*)d_in[2];
    const float* xW1 = (const float*)d_in[3];
    const float* xb1 = (const float*)d_in[4];
    const float* xW2 = (const float*)d_in[5];
    const float* xb2 = (const float*)d_in[6];
    const float* xW3 = (const float*)d_in[7];
    const float* xb3 = (const float*)d_in[8];
    const float* tW0 = (const float*)d_in[9];
    const float* tb0 = (const float*)d_in[10];
    const float* tW1 = (const float*)d_in[11];
    const float* tb1 = (const float*)d_in[12];
    const float* tW2 = (const float*)d_in[13];
    const float* tb2 = (const float*)d_in[14];
    const float* tW3 = (const float*)d_in[15];
    const float* tb3 = (const float*)d_in[16];

    _Float16* Wp = (_Float16*)d_ws;          // 6*65536 fp16 = 768 KB
    const int N = in_sizes[0] / 2;           // 1,000,000 (divisible by 64)

    prepack<<<1536, 256, 0, stream>>>(xW1, xW2, xW3, tW1, tW2, tW3, Wp);
    mlp_fused<<<N / 64, 512, 0, stream>>>(x, xW0, xb0, xb1, xb2, xb3,
                                          tW0, tb0, tb1, tb2, tb3,
                                          Wp, (float*)d_out);
}